// Round 15
// baseline (431.855 us; speedup 1.0000x reference)
//
#include <hip/hip_runtime.h>
#include <hip/hip_bf16.h>
#include <math.h>

#define B_   32
#define N_   8192
#define H_   128
#define G_   10
#define TOKS (B_*N_)
#define THREADS 768
#define WAVES 12
#define NTILES 32      // 32-token tiles per block
#define TPB 1024       // tokens per block -> grid = exactly 256 blocks (1/CU)
#define LDW 136        // padded row stride in shorts (272B)

typedef short bf16x8 __attribute__((ext_vector_type(8)));
typedef short bf16x4 __attribute__((ext_vector_type(4)));
typedef float f32x4 __attribute__((ext_vector_type(4)));

// ws layout: [0..1] loss_sum/mask_count floats; weight image at byte WS_IMG_OFF.
#define WS_IMG_OFF 256
#define IMG_BYTES  119232          // 3*128*136*2 + 3*16*136*2 + 3*128*4 + 3*16*4
#define IMG_INSTS  117             // ceil/1024; overshoot 576B lands in red/pad (safe)

struct __align__(16) SMem {
  short w1s[3][H_][LDW];   // W1^T bf16: [head][hidden j][input i]
  short w2s[3][16][LDW];   // W2^T bf16: [head][g pad16][hidden k]
  float b1s[3][H_];
  float b2s[3][16];
  float red[WAVES][3];     // staging overshoot lands here; written post-compute
  char  pad[640];
};

__device__ __forceinline__ short f2bf(float f) {
  __hip_bfloat16 h = __float2bfloat16(f);
  union { __hip_bfloat16 h; short s; } u; u.h = h;
  return u.s;
}

__device__ __forceinline__ void async_copy16(void* lds_uniform, const void* gsrc_perlane) {
  __builtin_amdgcn_global_load_lds(
      (const __attribute__((address_space(1))) unsigned int*)gsrc_perlane,
      (__attribute__((address_space(3))) unsigned int*)lds_uniform,
      16, 0, 0);
}

__global__ __launch_bounds__(64) void init_kernel(float* out, float* ws) {
  int t = threadIdx.x;
  if (t < 33) out[t] = 0.0f;
  if (t < 2)  ws[t]  = 0.0f;
}

__global__ __launch_bounds__(64) void fin_kernel(float* out, const float* ws) {
  if (threadIdx.x == 0) out[32] = ws[0] / fmaxf(ws[1], 1.0f);
}

__global__ __launch_bounds__(256) void prep_kernel(
    const float* __restrict__ w1_0, const float* __restrict__ b1_0,
    const float* __restrict__ w2_0, const float* __restrict__ b2_0,
    const float* __restrict__ w1_1, const float* __restrict__ b1_1,
    const float* __restrict__ w2_1, const float* __restrict__ b2_1,
    const float* __restrict__ w1_2, const float* __restrict__ b1_2,
    const float* __restrict__ w2_2, const float* __restrict__ b2_2,
    short* __restrict__ img) {
  const float* w1p[3] = {w1_0, w1_1, w1_2};
  const float* w2p[3] = {w2_0, w2_1, w2_2};
  const float* b1p[3] = {b1_0, b1_1, b1_2};
  const float* b2p[3] = {b2_0, b2_1, b2_2};
  int t = blockIdx.x * 256 + threadIdx.x;
  int stride = gridDim.x * 256;
  for (int idx = t; idx < 3*H_*LDW; idx += stride) {
    int h = idx / (H_*LDW), rem = idx - h*(H_*LDW);
    int j = rem / LDW, i = rem - j*LDW;
    img[idx] = (i < H_) ? f2bf(w1p[h][i*H_ + j]) : (short)0;
  }
  for (int idx = t; idx < 3*16*LDW; idx += stride) {
    int h = idx / (16*LDW), rem = idx - h*(16*LDW);
    int g = rem / LDW, k = rem - g*LDW;
    img[3*H_*LDW + idx] = (g < G_ && k < H_) ? f2bf(w2p[h][k*G_ + g]) : (short)0;
  }
  float* bimg = (float*)(img + 3*H_*LDW + 3*16*LDW);
  if (t < 3*H_ + 3*16) {
    if (t < 3*H_) { int h = t >> 7, j = t & 127; bimg[t] = b1p[h][j]; }
    else { int i2 = t - 3*H_; int h = i2 >> 4, g = i2 & 15;
           bimg[t] = (g < G_) ? b2p[h][g] : 0.0f; }
  }
}

template<int PREP>
__global__ __launch_bounds__(THREADS, 3)   // 12 waves = 3/SIMD -> 170-reg cap
void rtm_main(const float* __restrict__ feat,
              const float* __restrict__ dist,
              const int* __restrict__ dmask,
              const float* __restrict__ img,
              const float* __restrict__ w1_0, const float* __restrict__ b1_0,
              const float* __restrict__ w2_0, const float* __restrict__ b2_0,
              const float* __restrict__ w1_1, const float* __restrict__ b1_1,
              const float* __restrict__ w2_1, const float* __restrict__ b2_1,
              const float* __restrict__ w1_2, const float* __restrict__ b1_2,
              const float* __restrict__ w2_2, const float* __restrict__ b2_2,
              float* __restrict__ out, float* __restrict__ ws) {
  __shared__ SMem sm;

  const int tid  = threadIdx.x;
  const int wave = tid >> 6;
  const int lane = tid & 63;
  const int q  = lane >> 4;
  const int lg = lane & 15;
  const long bbase = (long)blockIdx.x * TPB;

  // ---- prologue: issue first tile's c01 feature loads + d/m ----
  float4 fv[8];            // half-tile prefetch buffer (c01 or c23 of one tile)
  float dcur[2]; int mcur[2];
  {
    const int t0 = wave;   // first tile of this wave (< 32 since WAVES=12)
#pragma unroll
    for (int mt = 0; mt < 2; ++mt) {
      long tok = bbase + t0*32 + mt*16 + lg;
      const float* fr = feat + tok * (long)H_;
      const float4* p0 = reinterpret_cast<const float4*>(fr + q*8);
      const float4* p1 = reinterpret_cast<const float4*>(fr + 32 + q*8);
      fv[mt*4+0] = p0[0];
      fv[mt*4+1] = p0[1];
      fv[mt*4+2] = p1[0];
      fv[mt*4+3] = p1[1];
      dcur[mt] = dist[tok];
      mcur[mt] = dmask[tok];
    }
  }

  // ---- stage weight image to LDS (async; once per CU, 12 waves) ----
  if constexpr (PREP) {
    char* smb = (char*)&sm;
    const char* gimg = (const char*)img;
    for (int i = wave; i < IMG_INSTS; i += WAVES)
      async_copy16(smb + i*1024, gimg + i*1024 + lane*16);
  } else {
    const float* w1p[3] = {w1_0, w1_1, w1_2};
    const float* w2p[3] = {w2_0, w2_1, w2_2};
    const float* b1p[3] = {b1_0, b1_1, b1_2};
    const float* b2p[3] = {b2_0, b2_1, b2_2};
    for (int h = 0; h < 3; ++h) {
      for (int idx = tid; idx < H_*H_; idx += THREADS) {
        int i = idx >> 7, j = idx & 127;
        sm.w1s[h][j][i] = f2bf(w1p[h][idx]);
      }
      for (int idx = tid; idx < 16*H_; idx += THREADS) {
        int g = idx >> 7, k = idx & 127;
        sm.w2s[h][g][k] = (g < G_) ? f2bf(w2p[h][(size_t)k*G_ + g]) : (short)0;
      }
      if (tid < H_) sm.b1s[h][tid] = b1p[h][tid];
      if (tid < 16) sm.b2s[h][tid] = (tid < G_) ? b2p[h][tid] : 0.0f;
    }
  }

  __syncthreads();   // weights visible; drains global_load_lds (covers tile-0 c01 too)

  float* out_score = out;
  float* out_pi = out + 33;
  float* out_mu = out + 33 + (size_t)TOKS*G_;
  float* out_sg = out + 33 + 2*(size_t)TOKS*G_;
  const float HLOG2PI = 0.91893853320467274f;
  const bool v0 = (q*4+0) < G_, v1 = (q*4+1) < G_, v2 = (q*4+2) < G_, v3 = (q*4+3) < G_;

  float accP = 0.f, accL = 0.f, accC = 0.f;

  // ---- tile loop: wave w handles tiles w, w+12, w+24 ----
  for (int t = wave; t < NTILES; t += WAVES) {
    // cvt c01 (loads issued last iteration / prologue)
    bf16x8 a1[2][4];   // B-frag: lane holds B[k=(lane>>4)*8+e][tok=lane&15]
#pragma unroll
    for (int mt = 0; mt < 2; ++mt)
#pragma unroll
      for (int c = 0; c < 2; ++c) {
        float4 lo = fv[mt*4 + c*2], hi = fv[mt*4 + c*2 + 1];
        bf16x8 a;
        a[0]=f2bf(lo.x); a[1]=f2bf(lo.y); a[2]=f2bf(lo.z); a[3]=f2bf(lo.w);
        a[4]=f2bf(hi.x); a[5]=f2bf(hi.y); a[6]=f2bf(hi.z); a[7]=f2bf(hi.w);
        a1[mt][c] = a;
      }
    // issue c23 of this tile
#pragma unroll
    for (int mt = 0; mt < 2; ++mt) {
      const float* fr = feat + (bbase + t*32 + mt*16 + lg) * (long)H_;
      const float4* p2 = reinterpret_cast<const float4*>(fr + 64 + q*8);
      const float4* p3 = reinterpret_cast<const float4*>(fr + 96 + q*8);
      fv[mt*4+0] = p2[0];
      fv[mt*4+1] = p2[1];
      fv[mt*4+2] = p3[0];
      fv[mt*4+3] = p3[1];
    }
    // cvt c23 (latency absorbed by other waves: 3/SIMD)
#pragma unroll
    for (int mt = 0; mt < 2; ++mt)
#pragma unroll
      for (int c = 2; c < 4; ++c) {
        float4 lo = fv[mt*4 + (c-2)*2], hi = fv[mt*4 + (c-2)*2 + 1];
        bf16x8 a;
        a[0]=f2bf(lo.x); a[1]=f2bf(lo.y); a[2]=f2bf(lo.z); a[3]=f2bf(lo.w);
        a[4]=f2bf(hi.x); a[5]=f2bf(hi.y); a[6]=f2bf(hi.z); a[7]=f2bf(hi.w);
        a1[mt][c] = a;
      }
    // issue next tile's c01 + d/m (covered by this tile's whole compute)
    const int tn = t + WAVES;
    float dnx[2]; int mnx[2];
    if (tn < NTILES) {
#pragma unroll
      for (int mt = 0; mt < 2; ++mt) {
        long tok = bbase + tn*32 + mt*16 + lg;
        const float* fr = feat + tok * (long)H_;
        const float4* p0 = reinterpret_cast<const float4*>(fr + q*8);
        const float4* p1 = reinterpret_cast<const float4*>(fr + 32 + q*8);
        fv[mt*4+0] = p0[0];
        fv[mt*4+1] = p0[1];
        fv[mt*4+2] = p1[0];
        fv[mt*4+3] = p1[1];
        dnx[mt] = dist[tok];
        mnx[mt] = dmask[tok];
      }
    }

    // ---- compute: 3 heads, layer1 in two nt-halves (acc[2][4] keeps regs small) ----
    f32x4 lgt[3][2];
#pragma unroll
    for (int h = 0; h < 3; ++h) {
      f32x4 lacc[2];
      lacc[0] = (f32x4){0.f,0.f,0.f,0.f};
      lacc[1] = (f32x4){0.f,0.f,0.f,0.f};
#pragma unroll
      for (int half = 0; half < 2; ++half) {
        f32x4 acc[2][4];
#pragma unroll
        for (int mt = 0; mt < 2; ++mt)
#pragma unroll
          for (int j = 0; j < 4; ++j) acc[mt][j] = (f32x4){0.f,0.f,0.f,0.f};
#pragma unroll
        for (int c = 0; c < 4; ++c) {
#pragma unroll
          for (int j = 0; j < 4; ++j) {
            int nt = half*4 + j;
            bf16x8 wfr = *reinterpret_cast<const bf16x8*>(&sm.w1s[h][nt*16 + lg][c*32 + q*8]);
            acc[0][j] = __builtin_amdgcn_mfma_f32_16x16x32_bf16(wfr, a1[0][c], acc[0][j], 0, 0, 0);
            acc[1][j] = __builtin_amdgcn_mfma_f32_16x16x32_bf16(wfr, a1[1][c], acc[1][j], 0, 0, 0);
          }
        }
        // bias+relu+pack -> register-resident K16 layer-2 (D layout == K16 B-frag)
#pragma unroll
        for (int mt = 0; mt < 2; ++mt) {
#pragma unroll
          for (int j = 0; j < 4; ++j) {
            int nt = half*4 + j;
            f32x4 b1v = *reinterpret_cast<const f32x4*>(&sm.b1s[h][nt*16 + q*4]);
            bf16x4 pkv;
#pragma unroll
            for (int r = 0; r < 4; ++r)
              pkv[r] = f2bf(fmaxf(acc[mt][j][r] + b1v[r], 0.0f));
            bf16x4 w2fr = *reinterpret_cast<const bf16x4*>(&sm.w2s[h][lg][nt*16 + q*4]);
            lacc[mt] = __builtin_amdgcn_mfma_f32_16x16x16bf16_1k(w2fr, pkv, lacc[mt], 0, 0, 0);
          }
        }
      }
      f32x4 b2v = *reinterpret_cast<const f32x4*>(&sm.b2s[h][q*4]);
      lgt[h][0] = lacc[0] + b2v;   // row = g = q*4+r, col = token = lg
      lgt[h][1] = lacc[1] + b2v;
    }

    // ---- epilogue (r13-proven form) ----
#pragma unroll
    for (int mt = 0; mt < 2; ++mt) {
      long tok = bbase + t*32 + mt*16 + lg;
      float d  = dcur[mt];
      bool  mk = (mcur[mt] != 0) && (d <= 8.0f);
      f32x4 LP = lgt[0][mt], LS = lgt[1][mt], LM = lgt[2][mt];

      float vm = v0 ? LP[0] : -INFINITY;
      if (v1) vm = fmaxf(vm, LP[1]);
      if (v2) vm = fmaxf(vm, LP[2]);
      if (v3) vm = fmaxf(vm, LP[3]);
      vm = fmaxf(vm, __shfl_xor(vm, 16));
      vm = fmaxf(vm, __shfl_xor(vm, 32));
      float e0 = v0 ? __expf(LP[0]-vm) : 0.f;
      float e1 = v1 ? __expf(LP[1]-vm) : 0.f;
      float e2 = v2 ? __expf(LP[2]-vm) : 0.f;
      float e3 = v3 ? __expf(LP[3]-vm) : 0.f;
      float ssum = e0+e1+e2+e3;
      ssum += __shfl_xor(ssum, 16);
      ssum += __shfl_xor(ssum, 32);
      float inv = 1.0f / ssum;
      float pi[4] = {e0*inv, e1*inv, e2*inv, e3*inv};

      float sg[4], mu[4], ll[4];
#pragma unroll
      for (int r = 0; r < 4; ++r) {
        sg[r] = (LS[r] > 0.f) ? (LS[r] + 1.4f) : (__expf(LS[r]) + 0.4f);
        mu[r] = (LM[r] > 0.f) ? (LM[r] + 1.0f) : __expf(LM[r]);
        float z = (d - mu[r]) / sg[r];
        ll[r] = -0.5f*z*z - __logf(sg[r]) - HLOG2PI;
      }

      if (q*4 < G_) {
        size_t o = (size_t)tok*G_ + q*4;
        *reinterpret_cast<float2*>(&out_pi[o]) = make_float2(pi[0], pi[1]);
        *reinterpret_cast<float2*>(&out_mu[o]) = make_float2(mu[0], mu[1]);
        *reinterpret_cast<float2*>(&out_sg[o]) = make_float2(sg[0], sg[1]);
        if (q*4+2 < G_) {
          *reinterpret_cast<float2*>(&out_pi[o+2]) = make_float2(pi[2], pi[3]);
          *reinterpret_cast<float2*>(&out_mu[o+2]) = make_float2(mu[2], mu[3]);
          *reinterpret_cast<float2*>(&out_sg[o+2]) = make_float2(sg[2], sg[3]);
        }
      }

      float a0 = v0 ? (__logf(pi[0]+1e-10f) + ll[0]) : -INFINITY;
      float a1x= v1 ? (__logf(pi[1]+1e-10f) + ll[1]) : -INFINITY;
      float a2 = v2 ? (__logf(pi[2]+1e-10f) + ll[2]) : -INFINITY;
      float a3 = v3 ? (__logf(pi[3]+1e-10f) + ll[3]) : -INFINITY;
      float m2 = fmaxf(fmaxf(a0,a1x), fmaxf(a2,a3));
      m2 = fmaxf(m2, __shfl_xor(m2, 16));
      m2 = fmaxf(m2, __shfl_xor(m2, 32));
      float s2 = (v0?__expf(a0-m2):0.f) + (v1?__expf(a1x-m2):0.f)
               + (v2?__expf(a2-m2):0.f) + (v3?__expf(a3-m2):0.f);
      s2 += __shfl_xor(s2, 16);
      s2 += __shfl_xor(s2, 32);
      float closs = -(m2 + __logf(s2));

      float s3 = (v0?__expf(ll[0])*pi[0]:0.f) + (v1?__expf(ll[1])*pi[1]:0.f)
               + (v2?__expf(ll[2])*pi[2]:0.f) + (v3?__expf(ll[3])*pi[3]:0.f);
      s3 += __shfl_xor(s3, 16);
      s3 += __shfl_xor(s3, 32);
      float prob = s3 / (d*d + 1e-10f);

      if (lane < 16 && mk) { accP += prob; accL += closs; accC += 1.f; }
    }

    if (tn < NTILES) { dcur[0]=dnx[0]; dcur[1]=dnx[1]; mcur[0]=mnx[0]; mcur[1]=mnx[1]; }
  }

  // ---- block reduce; block lies entirely in one batch b ----
  accP += __shfl_xor(accP, 1); accP += __shfl_xor(accP, 2);
  accP += __shfl_xor(accP, 4); accP += __shfl_xor(accP, 8);
  accL += __shfl_xor(accL, 1); accL += __shfl_xor(accL, 2);
  accL += __shfl_xor(accL, 4); accL += __shfl_xor(accL, 8);
  accC += __shfl_xor(accC, 1); accC += __shfl_xor(accC, 2);
  accC += __shfl_xor(accC, 4); accC += __shfl_xor(accC, 8);
  if (lane == 0) { sm.red[wave][0] = accP; sm.red[wave][1] = accL; sm.red[wave][2] = accC; }
  __syncthreads();
  if (tid == 0) {
    float sP = 0.f, sL = 0.f, sC = 0.f;
    for (int w = 0; w < WAVES; ++w) { sP += sm.red[w][0]; sL += sm.red[w][1]; sC += sm.red[w][2]; }
    int b = blockIdx.x >> 3;   // 8 blocks per batch (1024 tokens/block)
    atomicAdd(&out_score[b], sP);
    atomicAdd(&ws[0], sL);
    atomicAdd(&ws[1], sC);
  }
}

extern "C" void kernel_launch(void* const* d_in, const int* in_sizes, int n_in,
                              void* d_out, int out_size, void* d_ws, size_t ws_size,
                              hipStream_t stream) {
  const float* feat = (const float*)d_in[0];
  const float* dist = (const float*)d_in[1];
  const int* dmask = (const int*)d_in[2];
  float* out = (float*)d_out;
  float* ws  = (float*)d_ws;

  hipLaunchKernelGGL(init_kernel, dim3(1), dim3(64), 0, stream, out, ws);

  bool prep_ok = (ws_size >= (size_t)(WS_IMG_OFF + IMG_INSTS*1024));
  if (prep_ok) {
    short* img = (short*)((char*)d_ws + WS_IMG_OFF);
    hipLaunchKernelGGL(prep_kernel, dim3(116), dim3(256), 0, stream,
        (const float*)d_in[3],  (const float*)d_in[4],  (const float*)d_in[5],  (const float*)d_in[6],
        (const float*)d_in[7],  (const float*)d_in[8],  (const float*)d_in[9],  (const float*)d_in[10],
        (const float*)d_in[11], (const float*)d_in[12], (const float*)d_in[13], (const float*)d_in[14],
        img);
    hipLaunchKernelGGL((rtm_main<1>), dim3(TOKS/TPB), dim3(THREADS), 0, stream,
        feat, dist, dmask, (const float*)img,
        (const float*)d_in[3],  (const float*)d_in[4],  (const float*)d_in[5],  (const float*)d_in[6],
        (const float*)d_in[7],  (const float*)d_in[8],  (const float*)d_in[9],  (const float*)d_in[10],
        (const float*)d_in[11], (const float*)d_in[12], (const float*)d_in[13], (const float*)d_in[14],
        out, ws);
  } else {
    hipLaunchKernelGGL((rtm_main<0>), dim3(TOKS/TPB), dim3(THREADS), 0, stream,
        feat, dist, dmask, (const float*)nullptr,
        (const float*)d_in[3],  (const float*)d_in[4],  (const float*)d_in[5],  (const float*)d_in[6],
        (const float*)d_in[7],  (const float*)d_in[8],  (const float*)d_in[9],  (const float*)d_in[10],
        (const float*)d_in[11], (const float*)d_in[12], (const float*)d_in[13], (const float*)d_in[14],
        out, ws);
  }

  hipLaunchKernelGGL(fin_kernel, dim3(1), dim3(64), 0, stream, out, ws);
}

// Round 16
// 416.494 us; speedup vs baseline: 1.0369x; 1.0369x over previous
//
#include <hip/hip_runtime.h>
#include <hip/hip_bf16.h>
#include <math.h>

#define B_   32
#define N_   8192
#define H_   128
#define G_   10
#define TOKS (B_*N_)
#define THREADS 768
#define WAVES 12
#define NTILES 32      // 32-token tiles per block
#define TPB 1024       // tokens per block -> grid = exactly 256 blocks (1/CU)
#define LDW 136        // padded row stride in shorts (272B)

typedef short bf16x8 __attribute__((ext_vector_type(8)));
typedef short bf16x4 __attribute__((ext_vector_type(4)));
typedef float f32x4 __attribute__((ext_vector_type(4)));

// ws layout: [0..1] loss_sum/mask_count floats; weight image at byte WS_IMG_OFF.
#define WS_IMG_OFF 256
#define IMG_BYTES  119232          // 3*128*136*2 + 3*16*136*2 + 3*128*4 + 3*16*4
#define IMG_INSTS  117             // ceil/1024; overshoot 576B lands in red/pad (safe)

struct __align__(16) SMem {
  short w1s[3][H_][LDW];   // W1^T bf16: [head][hidden j][input i]
  short w2s[3][16][LDW];   // W2^T bf16: [head][g pad16][hidden k]
  float b1s[3][H_];
  float b2s[3][16];
  float red[WAVES][3];     // staging overshoot lands here; written post-compute
  char  pad[640];
};

__device__ __forceinline__ short f2bf(float f) {
  __hip_bfloat16 h = __float2bfloat16(f);
  union { __hip_bfloat16 h; short s; } u; u.h = h;
  return u.s;
}

__device__ __forceinline__ void async_copy16(void* lds_uniform, const void* gsrc_perlane) {
  __builtin_amdgcn_global_load_lds(
      (const __attribute__((address_space(1))) unsigned int*)gsrc_perlane,
      (__attribute__((address_space(3))) unsigned int*)lds_uniform,
      16, 0, 0);
}

__global__ __launch_bounds__(64) void init_kernel(float* out, float* ws) {
  int t = threadIdx.x;
  if (t < 33) out[t] = 0.0f;
  if (t < 2)  ws[t]  = 0.0f;
}

__global__ __launch_bounds__(64) void fin_kernel(float* out, const float* ws) {
  if (threadIdx.x == 0) out[32] = ws[0] / fmaxf(ws[1], 1.0f);
}

__global__ __launch_bounds__(256) void prep_kernel(
    const float* __restrict__ w1_0, const float* __restrict__ b1_0,
    const float* __restrict__ w2_0, const float* __restrict__ b2_0,
    const float* __restrict__ w1_1, const float* __restrict__ b1_1,
    const float* __restrict__ w2_1, const float* __restrict__ b2_1,
    const float* __restrict__ w1_2, const float* __restrict__ b1_2,
    const float* __restrict__ w2_2, const float* __restrict__ b2_2,
    short* __restrict__ img) {
  const float* w1p[3] = {w1_0, w1_1, w1_2};
  const float* w2p[3] = {w2_0, w2_1, w2_2};
  const float* b1p[3] = {b1_0, b1_1, b1_2};
  const float* b2p[3] = {b2_0, b2_1, b2_2};
  int t = blockIdx.x * 256 + threadIdx.x;
  int stride = gridDim.x * 256;
  for (int idx = t; idx < 3*H_*LDW; idx += stride) {
    int h = idx / (H_*LDW), rem = idx - h*(H_*LDW);
    int j = rem / LDW, i = rem - j*LDW;
    img[idx] = (i < H_) ? f2bf(w1p[h][i*H_ + j]) : (short)0;
  }
  for (int idx = t; idx < 3*16*LDW; idx += stride) {
    int h = idx / (16*LDW), rem = idx - h*(16*LDW);
    int g = rem / LDW, k = rem - g*LDW;
    img[3*H_*LDW + idx] = (g < G_ && k < H_) ? f2bf(w2p[h][k*G_ + g]) : (short)0;
  }
  float* bimg = (float*)(img + 3*H_*LDW + 3*16*LDW);
  if (t < 3*H_ + 3*16) {
    if (t < 3*H_) { int h = t >> 7, j = t & 127; bimg[t] = b1p[h][j]; }
    else { int i2 = t - 3*H_; int h = i2 >> 4, g = i2 & 15;
           bimg[t] = (g < G_) ? b2p[h][g] : 0.0f; }
  }
}

template<int PREP>
__global__ __launch_bounds__(THREADS, 2)   // cap 256 (128/128 split): NO spill pressure;
                                           // actual use ~<=160 -> HW gives 3 waves/SIMD
void rtm_main(const float* __restrict__ feat,
              const float* __restrict__ dist,
              const int* __restrict__ dmask,
              const float* __restrict__ img,
              const float* __restrict__ w1_0, const float* __restrict__ b1_0,
              const float* __restrict__ w2_0, const float* __restrict__ b2_0,
              const float* __restrict__ w1_1, const float* __restrict__ b1_1,
              const float* __restrict__ w2_1, const float* __restrict__ b2_1,
              const float* __restrict__ w1_2, const float* __restrict__ b1_2,
              const float* __restrict__ w2_2, const float* __restrict__ b2_2,
              float* __restrict__ out, float* __restrict__ ws) {
  __shared__ SMem sm;

  const int tid  = threadIdx.x;
  const int wave = tid >> 6;
  const int lane = tid & 63;
  const int q  = lane >> 4;
  const int lg = lane & 15;
  const long bbase = (long)blockIdx.x * TPB;

  // ---- prologue: issue c01 of first tile (t0 = wave) + d/m ----
  float4 fv[8];            // HALF-tile buffer (c01 or c23; 2 chunks x 2 float4 x 2 mt)
  float dcur[2]; int mcur[2];
#pragma unroll
  for (int mt = 0; mt < 2; ++mt) {
    long tok = bbase + wave*32 + mt*16 + lg;
    const float* fr = feat + tok * (long)H_;
    const float4* p0 = reinterpret_cast<const float4*>(fr + q*8);
    const float4* p1 = reinterpret_cast<const float4*>(fr + 32 + q*8);
    fv[mt*4+0] = p0[0];
    fv[mt*4+1] = p0[1];
    fv[mt*4+2] = p1[0];
    fv[mt*4+3] = p1[1];
    dcur[mt] = dist[tok];
    mcur[mt] = dmask[tok];
  }

  // ---- stage weight image to LDS (async; once per CU; 12 waves) ----
  if constexpr (PREP) {
    char* smb = (char*)&sm;
    const char* gimg = (const char*)img;
    for (int i = wave; i < IMG_INSTS; i += WAVES)
      async_copy16(smb + i*1024, gimg + i*1024 + lane*16);
  } else {
    const float* w1p[3] = {w1_0, w1_1, w1_2};
    const float* w2p[3] = {w2_0, w2_1, w2_2};
    const float* b1p[3] = {b1_0, b1_1, b1_2};
    const float* b2p[3] = {b2_0, b2_1, b2_2};
    for (int h = 0; h < 3; ++h) {
      for (int idx = tid; idx < H_*H_; idx += THREADS) {
        int i = idx >> 7, j = idx & 127;
        sm.w1s[h][j][i] = f2bf(w1p[h][idx]);
      }
      for (int idx = tid; idx < 16*H_; idx += THREADS) {
        int g = idx >> 7, k = idx & 127;
        sm.w2s[h][g][k] = (g < G_) ? f2bf(w2p[h][(size_t)k*G_ + g]) : (short)0;
      }
      if (tid < H_) sm.b1s[h][tid] = b1p[h][tid];
      if (tid < 16) sm.b2s[h][tid] = (tid < G_) ? b2p[h][tid] : 0.0f;
    }
  }

  __syncthreads();   // weights visible (also drains c01(t0) loads)

  // cvt c01(t0); issue c23(t0)
  bf16x8 a1[2][4];   // B-frag: lane holds B[k=(lane>>4)*8+e][tok=lane&15]
#pragma unroll
  for (int mt = 0; mt < 2; ++mt)
#pragma unroll
    for (int c = 0; c < 2; ++c) {
      float4 lo = fv[mt*4 + c*2], hi = fv[mt*4 + c*2 + 1];
      bf16x8 a;
      a[0]=f2bf(lo.x); a[1]=f2bf(lo.y); a[2]=f2bf(lo.z); a[3]=f2bf(lo.w);
      a[4]=f2bf(hi.x); a[5]=f2bf(hi.y); a[6]=f2bf(hi.z); a[7]=f2bf(hi.w);
      a1[mt][c] = a;
    }
#pragma unroll
  for (int mt = 0; mt < 2; ++mt) {
    const float* fr = feat + (bbase + wave*32 + mt*16 + lg) * (long)H_;
    const float4* p2 = reinterpret_cast<const float4*>(fr + 64 + q*8);
    const float4* p3 = reinterpret_cast<const float4*>(fr + 96 + q*8);
    fv[mt*4+0] = p2[0];
    fv[mt*4+1] = p2[1];
    fv[mt*4+2] = p3[0];
    fv[mt*4+3] = p3[1];
  }

  float* out_score = out;
  float* out_pi = out + 33;
  float* out_mu = out + 33 + (size_t)TOKS*G_;
  float* out_sg = out + 33 + 2*(size_t)TOKS*G_;
  const float HLOG2PI = 0.91893853320467274f;
  const bool v0 = (q*4+0) < G_, v1 = (q*4+1) < G_, v2 = (q*4+2) < G_, v3 = (q*4+3) < G_;

  float accP = 0.f, accL = 0.f, accC = 0.f;

  // ---- tile loop: wave w handles tiles w, w+12, w+24 ----
  for (int t = wave; t < NTILES; t += WAVES) {
    // cvt c23(t)  [cover: previous tile's epilogue / prologue]
#pragma unroll
    for (int mt = 0; mt < 2; ++mt)
#pragma unroll
      for (int c = 2; c < 4; ++c) {
        float4 lo = fv[mt*4 + (c-2)*2], hi = fv[mt*4 + (c-2)*2 + 1];
        bf16x8 a;
        a[0]=f2bf(lo.x); a[1]=f2bf(lo.y); a[2]=f2bf(lo.z); a[3]=f2bf(lo.w);
        a[4]=f2bf(hi.x); a[5]=f2bf(hi.y); a[6]=f2bf(hi.z); a[7]=f2bf(hi.w);
        a1[mt][c] = a;
      }
    const int tn = t + WAVES;
    float dnx[2]; int mnx[2];
    if (tn < NTILES) {   // issue c01(tn) + d/m  [cover: layer1+2 below]
#pragma unroll
      for (int mt = 0; mt < 2; ++mt) {
        long tok = bbase + tn*32 + mt*16 + lg;
        const float* fr = feat + tok * (long)H_;
        const float4* p0 = reinterpret_cast<const float4*>(fr + q*8);
        const float4* p1 = reinterpret_cast<const float4*>(fr + 32 + q*8);
        fv[mt*4+0] = p0[0];
        fv[mt*4+1] = p0[1];
        fv[mt*4+2] = p1[0];
        fv[mt*4+3] = p1[1];
        dnx[mt] = dist[tok];
        mnx[mt] = dmask[tok];
      }
    }

    // ---- layer1 (two nt-halves, acc[2][4]=32 agpr) + register-resident layer2 ----
    f32x4 lgt[3][2];
#pragma unroll
    for (int h = 0; h < 3; ++h) {
      f32x4 lacc0 = (f32x4){0.f,0.f,0.f,0.f};
      f32x4 lacc1 = (f32x4){0.f,0.f,0.f,0.f};
#pragma unroll
      for (int half = 0; half < 2; ++half) {
        f32x4 acc[2][4];
#pragma unroll
        for (int mt = 0; mt < 2; ++mt)
#pragma unroll
          for (int j = 0; j < 4; ++j) acc[mt][j] = (f32x4){0.f,0.f,0.f,0.f};
#pragma unroll
        for (int c = 0; c < 4; ++c) {
#pragma unroll
          for (int j = 0; j < 4; ++j) {
            int nt = half*4 + j;
            bf16x8 wfr = *reinterpret_cast<const bf16x8*>(&sm.w1s[h][nt*16 + lg][c*32 + q*8]);
            acc[0][j] = __builtin_amdgcn_mfma_f32_16x16x32_bf16(wfr, a1[0][c], acc[0][j], 0, 0, 0);
            acc[1][j] = __builtin_amdgcn_mfma_f32_16x16x32_bf16(wfr, a1[1][c], acc[1][j], 0, 0, 0);
          }
        }
#pragma unroll
        for (int j = 0; j < 4; ++j) {
          int nt = half*4 + j;
          f32x4 b1v = *reinterpret_cast<const f32x4*>(&sm.b1s[h][nt*16 + q*4]);
          bf16x4 w2fr = *reinterpret_cast<const bf16x4*>(&sm.w2s[h][lg][nt*16 + q*4]);
          bf16x4 pk0, pk1;
#pragma unroll
          for (int r = 0; r < 4; ++r) {
            pk0[r] = f2bf(fmaxf(acc[0][j][r] + b1v[r], 0.0f));
            pk1[r] = f2bf(fmaxf(acc[1][j][r] + b1v[r], 0.0f));
          }
          lacc0 = __builtin_amdgcn_mfma_f32_16x16x16bf16_1k(w2fr, pk0, lacc0, 0, 0, 0);
          lacc1 = __builtin_amdgcn_mfma_f32_16x16x16bf16_1k(w2fr, pk1, lacc1, 0, 0, 0);
        }
      }
      f32x4 b2v = *reinterpret_cast<const f32x4*>(&sm.b2s[h][q*4]);
      lgt[h][0] = lacc0 + b2v;   // row = g = q*4+r, col = token = lg
      lgt[h][1] = lacc1 + b2v;
    }

    // cvt c01(tn) -> a1[01] (a1 no longer needed); issue c23(tn)  [cover: epilogue below]
    if (tn < NTILES) {
#pragma unroll
      for (int mt = 0; mt < 2; ++mt)
#pragma unroll
        for (int c = 0; c < 2; ++c) {
          float4 lo = fv[mt*4 + c*2], hi = fv[mt*4 + c*2 + 1];
          bf16x8 a;
          a[0]=f2bf(lo.x); a[1]=f2bf(lo.y); a[2]=f2bf(lo.z); a[3]=f2bf(lo.w);
          a[4]=f2bf(hi.x); a[5]=f2bf(hi.y); a[6]=f2bf(hi.z); a[7]=f2bf(hi.w);
          a1[mt][c] = a;
        }
#pragma unroll
      for (int mt = 0; mt < 2; ++mt) {
        const float* fr = feat + (bbase + tn*32 + mt*16 + lg) * (long)H_;
        const float4* p2 = reinterpret_cast<const float4*>(fr + 64 + q*8);
        const float4* p3 = reinterpret_cast<const float4*>(fr + 96 + q*8);
        fv[mt*4+0] = p2[0];
        fv[mt*4+1] = p2[1];
        fv[mt*4+2] = p3[0];
        fv[mt*4+3] = p3[1];
      }
    }

    // ---- epilogue tile t (r13-proven form) ----
#pragma unroll
    for (int mt = 0; mt < 2; ++mt) {
      long tok = bbase + t*32 + mt*16 + lg;
      float d  = dcur[mt];
      bool  mk = (mcur[mt] != 0) && (d <= 8.0f);
      f32x4 LP = lgt[0][mt], LS = lgt[1][mt], LM = lgt[2][mt];

      float vm = v0 ? LP[0] : -INFINITY;
      if (v1) vm = fmaxf(vm, LP[1]);
      if (v2) vm = fmaxf(vm, LP[2]);
      if (v3) vm = fmaxf(vm, LP[3]);
      vm = fmaxf(vm, __shfl_xor(vm, 16));
      vm = fmaxf(vm, __shfl_xor(vm, 32));
      float e0 = v0 ? __expf(LP[0]-vm) : 0.f;
      float e1 = v1 ? __expf(LP[1]-vm) : 0.f;
      float e2 = v2 ? __expf(LP[2]-vm) : 0.f;
      float e3 = v3 ? __expf(LP[3]-vm) : 0.f;
      float ssum = e0+e1+e2+e3;
      ssum += __shfl_xor(ssum, 16);
      ssum += __shfl_xor(ssum, 32);
      float inv = 1.0f / ssum;
      float pi[4] = {e0*inv, e1*inv, e2*inv, e3*inv};

      float sg[4], mu[4], ll[4];
#pragma unroll
      for (int r = 0; r < 4; ++r) {
        sg[r] = (LS[r] > 0.f) ? (LS[r] + 1.4f) : (__expf(LS[r]) + 0.4f);
        mu[r] = (LM[r] > 0.f) ? (LM[r] + 1.0f) : __expf(LM[r]);
        float z = (d - mu[r]) / sg[r];
        ll[r] = -0.5f*z*z - __logf(sg[r]) - HLOG2PI;
      }

      if (q*4 < G_) {
        size_t o = (size_t)tok*G_ + q*4;
        *reinterpret_cast<float2*>(&out_pi[o]) = make_float2(pi[0], pi[1]);
        *reinterpret_cast<float2*>(&out_mu[o]) = make_float2(mu[0], mu[1]);
        *reinterpret_cast<float2*>(&out_sg[o]) = make_float2(sg[0], sg[1]);
        if (q*4+2 < G_) {
          *reinterpret_cast<float2*>(&out_pi[o+2]) = make_float2(pi[2], pi[3]);
          *reinterpret_cast<float2*>(&out_mu[o+2]) = make_float2(mu[2], mu[3]);
          *reinterpret_cast<float2*>(&out_sg[o+2]) = make_float2(sg[2], sg[3]);
        }
      }

      float a0 = v0 ? (__logf(pi[0]+1e-10f) + ll[0]) : -INFINITY;
      float a1x= v1 ? (__logf(pi[1]+1e-10f) + ll[1]) : -INFINITY;
      float a2 = v2 ? (__logf(pi[2]+1e-10f) + ll[2]) : -INFINITY;
      float a3 = v3 ? (__logf(pi[3]+1e-10f) + ll[3]) : -INFINITY;
      float m2 = fmaxf(fmaxf(a0,a1x), fmaxf(a2,a3));
      m2 = fmaxf(m2, __shfl_xor(m2, 16));
      m2 = fmaxf(m2, __shfl_xor(m2, 32));
      float s2 = (v0?__expf(a0-m2):0.f) + (v1?__expf(a1x-m2):0.f)
               + (v2?__expf(a2-m2):0.f) + (v3?__expf(a3-m2):0.f);
      s2 += __shfl_xor(s2, 16);
      s2 += __shfl_xor(s2, 32);
      float closs = -(m2 + __logf(s2));

      float s3 = (v0?__expf(ll[0])*pi[0]:0.f) + (v1?__expf(ll[1])*pi[1]:0.f)
               + (v2?__expf(ll[2])*pi[2]:0.f) + (v3?__expf(ll[3])*pi[3]:0.f);
      s3 += __shfl_xor(s3, 16);
      s3 += __shfl_xor(s3, 32);
      float prob = s3 / (d*d + 1e-10f);

      if (lane < 16 && mk) { accP += prob; accL += closs; accC += 1.f; }
    }

    if (tn < NTILES) { dcur[0]=dnx[0]; dcur[1]=dnx[1]; mcur[0]=mnx[0]; mcur[1]=mnx[1]; }
  }

  // ---- block reduce; block lies entirely in one batch b ----
  accP += __shfl_xor(accP, 1); accP += __shfl_xor(accP, 2);
  accP += __shfl_xor(accP, 4); accP += __shfl_xor(accP, 8);
  accL += __shfl_xor(accL, 1); accL += __shfl_xor(accL, 2);
  accL += __shfl_xor(accL, 4); accL += __shfl_xor(accL, 8);
  accC += __shfl_xor(accC, 1); accC += __shfl_xor(accC, 2);
  accC += __shfl_xor(accC, 4); accC += __shfl_xor(accC, 8);
  if (lane == 0) { sm.red[wave][0] = accP; sm.red[wave][1] = accL; sm.red[wave][2] = accC; }
  __syncthreads();
  if (tid == 0) {
    float sP = 0.f, sL = 0.f, sC = 0.f;
    for (int w = 0; w < WAVES; ++w) { sP += sm.red[w][0]; sL += sm.red[w][1]; sC += sm.red[w][2]; }
    int b = blockIdx.x >> 3;   // 8 blocks per batch (1024 tokens/block)
    atomicAdd(&out_score[b], sP);
    atomicAdd(&ws[0], sL);
    atomicAdd(&ws[1], sC);
  }
}

extern "C" void kernel_launch(void* const* d_in, const int* in_sizes, int n_in,
                              void* d_out, int out_size, void* d_ws, size_t ws_size,
                              hipStream_t stream) {
  const float* feat = (const float*)d_in[0];
  const float* dist = (const float*)d_in[1];
  const int* dmask = (const int*)d_in[2];
  float* out = (float*)d_out;
  float* ws  = (float*)d_ws;

  hipLaunchKernelGGL(init_kernel, dim3(1), dim3(64), 0, stream, out, ws);

  bool prep_ok = (ws_size >= (size_t)(WS_IMG_OFF + IMG_INSTS*1024));
  if (prep_ok) {
    short* img = (short*)((char*)d_ws + WS_IMG_OFF);
    hipLaunchKernelGGL(prep_kernel, dim3(116), dim3(256), 0, stream,
        (const float*)d_in[3],  (const float*)d_in[4],  (const float*)d_in[5],  (const float*)d_in[6],
        (const float*)d_in[7],  (const float*)d_in[8],  (const float*)d_in[9],  (const float*)d_in[10],
        (const float*)d_in[11], (const float*)d_in[12], (const float*)d_in[13], (const float*)d_in[14],
        img);
    hipLaunchKernelGGL((rtm_main<1>), dim3(TOKS/TPB), dim3(THREADS), 0, stream,
        feat, dist, dmask, (const float*)img,
        (const float*)d_in[3],  (const float*)d_in[4],  (const float*)d_in[5],  (const float*)d_in[6],
        (const float*)d_in[7],  (const float*)d_in[8],  (const float*)d_in[9],  (const float*)d_in[10],
        (const float*)d_in[11], (const float*)d_in[12], (const float*)d_in[13], (const float*)d_in[14],
        out, ws);
  } else {
    hipLaunchKernelGGL((rtm_main<0>), dim3(TOKS/TPB), dim3(THREADS), 0, stream,
        feat, dist, dmask, (const float*)nullptr,
        (const float*)d_in[3],  (const float*)d_in[4],  (const float*)d_in[5],  (const float*)d_in[6],
        (const float*)d_in[7],  (const float*)d_in[8],  (const float*)d_in[9],  (const float*)d_in[10],
        (const float*)d_in[11], (const float*)d_in[12], (const float*)d_in[13], (const float*)d_in[14],
        out, ws);
  }

  hipLaunchKernelGGL(fin_kernel, dim3(1), dim3(64), 0, stream, out, ws);
}

// Round 17
// 65.077 us; speedup vs baseline: 6.6361x; 6.4001x over previous
//
#include <hip/hip_runtime.h>
#include <hip/hip_bf16.h>
#include <math.h>

#define B_   32
#define N_   8192
#define H_   128
#define G_   10
#define TOKS (B_*N_)
#define THREADS 512
#define WAVES 8
#define NITER 4
#define TPB 1024   // 8 waves x 32 tok/tile x 4 tiles -> grid = exactly 256 blocks (1/CU)
#define LDW 136    // padded row stride in shorts (272B)

typedef short bf16x8 __attribute__((ext_vector_type(8)));
typedef short bf16x4 __attribute__((ext_vector_type(4)));
typedef float f32x4 __attribute__((ext_vector_type(4)));

// ws layout: [0..1] loss_sum/mask_count floats; weight image at byte WS_IMG_OFF.
#define WS_IMG_OFF 256
#define IMG_BYTES  119232          // 3*128*136*2 + 3*16*136*2 + 3*128*4 + 3*16*4
#define IMG_INSTS  117             // ceil/1024; overshoot 576B lands in red/pad (safe)

struct __align__(16) SMem {
  short w1s[3][H_][LDW];   // W1^T bf16: [head][hidden j][input i]
  short w2s[3][16][LDW];   // W2^T bf16: [head][g pad16][hidden k]
  float b1s[3][H_];
  float b2s[3][16];
  float red[WAVES][3];     // staging overshoot lands here; written post-compute
  char  pad[640];
};

__device__ __forceinline__ short f2bf(float f) {
  __hip_bfloat16 h = __float2bfloat16(f);
  union { __hip_bfloat16 h; short s; } u; u.h = h;
  return u.s;
}

__device__ __forceinline__ void async_copy16(void* lds_uniform, const void* gsrc_perlane) {
  __builtin_amdgcn_global_load_lds(
      (const __attribute__((address_space(1))) unsigned int*)gsrc_perlane,
      (__attribute__((address_space(3))) unsigned int*)lds_uniform,
      16, 0, 0);
}

__global__ __launch_bounds__(64) void init_kernel(float* out, float* ws) {
  int t = threadIdx.x;
  if (t < 33) out[t] = 0.0f;
  if (t < 2)  ws[t]  = 0.0f;
}

__global__ __launch_bounds__(64) void fin_kernel(float* out, const float* ws) {
  if (threadIdx.x == 0) out[32] = ws[0] / fmaxf(ws[1], 1.0f);
}

__global__ __launch_bounds__(256) void prep_kernel(
    const float* __restrict__ w1_0, const float* __restrict__ b1_0,
    const float* __restrict__ w2_0, const float* __restrict__ b2_0,
    const float* __restrict__ w1_1, const float* __restrict__ b1_1,
    const float* __restrict__ w2_1, const float* __restrict__ b2_1,
    const float* __restrict__ w1_2, const float* __restrict__ b1_2,
    const float* __restrict__ w2_2, const float* __restrict__ b2_2,
    short* __restrict__ img) {
  const float* w1p[3] = {w1_0, w1_1, w1_2};
  const float* w2p[3] = {w2_0, w2_1, w2_2};
  const float* b1p[3] = {b1_0, b1_1, b1_2};
  const float* b2p[3] = {b2_0, b2_1, b2_2};
  int t = blockIdx.x * 256 + threadIdx.x;
  int stride = gridDim.x * 256;
  for (int idx = t; idx < 3*H_*LDW; idx += stride) {
    int h = idx / (H_*LDW), rem = idx - h*(H_*LDW);
    int j = rem / LDW, i = rem - j*LDW;
    img[idx] = (i < H_) ? f2bf(w1p[h][i*H_ + j]) : (short)0;
  }
  for (int idx = t; idx < 3*16*LDW; idx += stride) {
    int h = idx / (16*LDW), rem = idx - h*(16*LDW);
    int g = rem / LDW, k = rem - g*LDW;
    img[3*H_*LDW + idx] = (g < G_ && k < H_) ? f2bf(w2p[h][k*G_ + g]) : (short)0;
  }
  float* bimg = (float*)(img + 3*H_*LDW + 3*16*LDW);
  if (t < 3*H_ + 3*16) {
    if (t < 3*H_) { int h = t >> 7, j = t & 127; bimg[t] = b1p[h][j]; }
    else { int i2 = t - 3*H_; int h = i2 >> 4, g = i2 & 15;
           bimg[t] = (g < G_) ? b2p[h][g] : 0.0f; }
  }
}

template<int PREP>
__global__ __launch_bounds__(THREADS, 2)   // 256-reg cap (128/128 split), r13-proven
void rtm_main(const float* __restrict__ feat,
              const float* __restrict__ dist,
              const int* __restrict__ dmask,
              const float* __restrict__ img,
              const float* __restrict__ w1_0, const float* __restrict__ b1_0,
              const float* __restrict__ w2_0, const float* __restrict__ b2_0,
              const float* __restrict__ w1_1, const float* __restrict__ b1_1,
              const float* __restrict__ w2_1, const float* __restrict__ b2_1,
              const float* __restrict__ w1_2, const float* __restrict__ b1_2,
              const float* __restrict__ w2_2, const float* __restrict__ b2_2,
              float* __restrict__ out, float* __restrict__ ws) {
  __shared__ SMem sm;

  const int tid  = threadIdx.x;
  const int wave = tid >> 6;
  const int lane = tid & 63;
  const int q  = lane >> 4;
  const int lg = lane & 15;
  const long wbase = (long)blockIdx.x * TPB + (long)wave * (32*NITER);

  // ---- prologue: issue tile-0 loads ----
  float4 fv[2][8];
  float dpre[2]; int mpre[2];
#pragma unroll
  for (int mt = 0; mt < 2; ++mt) {
    const float* fr = feat + (wbase + mt*16 + lg) * (long)H_;
#pragma unroll
    for (int c = 0; c < 4; ++c) {
      const float4* p = reinterpret_cast<const float4*>(fr + c*32 + q*8);
      fv[mt][2*c]   = p[0];
      fv[mt][2*c+1] = p[1];
    }
    dpre[mt] = dist[wbase + mt*16 + lg];
    mpre[mt] = dmask[wbase + mt*16 + lg];
  }

  // ---- stage weight image to LDS (async; once per CU) ----
  if constexpr (PREP) {
    char* smb = (char*)&sm;
    const char* gimg = (const char*)img;
    for (int i = wave; i < IMG_INSTS; i += WAVES)
      async_copy16(smb + i*1024, gimg + i*1024 + lane*16);
  } else {
    const float* w1p[3] = {w1_0, w1_1, w1_2};
    const float* w2p[3] = {w2_0, w2_1, w2_2};
    const float* b1p[3] = {b1_0, b1_1, b1_2};
    const float* b2p[3] = {b2_0, b2_1, b2_2};
    for (int h = 0; h < 3; ++h) {
      for (int idx = tid; idx < H_*H_; idx += THREADS) {
        int i = idx >> 7, j = idx & 127;
        sm.w1s[h][j][i] = f2bf(w1p[h][idx]);
      }
      for (int idx = tid; idx < 16*H_; idx += THREADS) {
        int g = idx >> 7, k = idx & 127;
        sm.w2s[h][g][k] = (g < G_) ? f2bf(w2p[h][(size_t)k*G_ + g]) : (short)0;
      }
      if (tid < H_) sm.b1s[h][tid] = b1p[h][tid];
      if (tid < 16) sm.b2s[h][tid] = (tid < G_) ? b2p[h][tid] : 0.0f;
    }
  }

  // ---- convert tile 0 while staging is in flight ----
  bf16x8 a1[2][4];   // B-frag (K=32): lane holds B[k=(lane>>4)*8+e][tok=lane&15]
#pragma unroll
  for (int mt = 0; mt < 2; ++mt)
#pragma unroll
    for (int c = 0; c < 4; ++c) {
      float4 lo = fv[mt][2*c], hi = fv[mt][2*c+1];
      bf16x8 a;
      a[0]=f2bf(lo.x); a[1]=f2bf(lo.y); a[2]=f2bf(lo.z); a[3]=f2bf(lo.w);
      a[4]=f2bf(hi.x); a[5]=f2bf(hi.y); a[6]=f2bf(hi.z); a[7]=f2bf(hi.w);
      a1[mt][c] = a;
    }

  __syncthreads();   // weights visible; drains global_load_lds

  float* out_score = out;
  float* out_pi = out + 33;
  float* out_mu = out + 33 + (size_t)TOKS*G_;
  float* out_sg = out + 33 + 2*(size_t)TOKS*G_;
  const float HLOG2PI = 0.91893853320467274f;
  const bool v0 = (q*4+0) < G_, v1 = (q*4+1) < G_, v2 = (q*4+2) < G_, v3 = (q*4+3) < G_;

  float accP = 0.f, accL = 0.f, accC = 0.f;

  // ---- pipelined tile loop ----
#pragma unroll
  for (int s = 0; s < NITER; ++s) {
    float dnx[2]; int mnx[2];
    if (s + 1 < NITER) {
#pragma unroll
      for (int mt = 0; mt < 2; ++mt) {
        const float* fr = feat + (wbase + (s+1)*32 + mt*16 + lg) * (long)H_;
#pragma unroll
        for (int c = 0; c < 4; ++c) {
          const float4* p = reinterpret_cast<const float4*>(fr + c*32 + q*8);
          fv[mt][2*c]   = p[0];
          fv[mt][2*c+1] = p[1];
        }
        dnx[mt] = dist[wbase + (s+1)*32 + mt*16 + lg];
        mnx[mt] = dmask[wbase + (s+1)*32 + mt*16 + lg];
      }
    }

    // ---- compute tile s ----
    f32x4 lgt[3][2];
#pragma unroll
    for (int h = 0; h < 3; ++h) {
      // W2^T K16 A-frags (r13 layout): lane = W2^T[g=lg][k=nt*16+q*4+e]
      bf16x4 w2fr[8];
#pragma unroll
      for (int nt = 0; nt < 8; ++nt)
        w2fr[nt] = *reinterpret_cast<const bf16x4*>(&sm.w2s[h][lg][nt*16 + q*4]);

      // layer 1: init accumulator with BIAS (saves the add at pack, halves b1 reads)
      f32x4 acc[2][8];
#pragma unroll
      for (int nt = 0; nt < 8; ++nt) {
        f32x4 b1v = *reinterpret_cast<const f32x4*>(&sm.b1s[h][nt*16 + q*4]);
        acc[0][nt] = b1v;
        acc[1][nt] = b1v;
      }
#pragma unroll
      for (int c = 0; c < 4; ++c) {
#pragma unroll
        for (int nt = 0; nt < 8; ++nt) {
          bf16x8 wfr = *reinterpret_cast<const bf16x8*>(&sm.w1s[h][nt*16 + lg][c*32 + q*8]);
          acc[0][nt] = __builtin_amdgcn_mfma_f32_16x16x32_bf16(wfr, a1[0][c], acc[0][nt], 0, 0, 0);
          acc[1][nt] = __builtin_amdgcn_mfma_f32_16x16x32_bf16(wfr, a1[1][c], acc[1][nt], 0, 0, 0);
        }
      }
#pragma unroll
      for (int mt = 0; mt < 2; ++mt) {
        // layer 2 in registers: init chains with b2v (split across two chains)
        f32x4 b2v = *reinterpret_cast<const f32x4*>(&sm.b2s[h][q*4]);
        f32x4 lacc0 = b2v;
        f32x4 lacc1 = (f32x4){0.f,0.f,0.f,0.f};
#pragma unroll
        for (int nt = 0; nt < 8; ++nt) {
          bf16x4 pkv;
#pragma unroll
          for (int r = 0; r < 4; ++r)
            pkv[r] = f2bf(fmaxf(acc[mt][nt][r], 0.0f));
          if (nt & 1)
            lacc1 = __builtin_amdgcn_mfma_f32_16x16x16bf16_1k(w2fr[nt], pkv, lacc1, 0, 0, 0);
          else
            lacc0 = __builtin_amdgcn_mfma_f32_16x16x16bf16_1k(w2fr[nt], pkv, lacc0, 0, 0, 0);
        }
        lgt[h][mt] = lacc0 + lacc1;   // row = g = q*4+r, col = token = lg
      }
    }

    // ---- epilogue tile s (r13 form + s3 = s2*exp(m2) fusion) ----
#pragma unroll
    for (int mt = 0; mt < 2; ++mt) {
      long tok = wbase + s*32 + mt*16 + lg;
      float d  = dpre[mt];
      bool  mk = (mpre[mt] != 0) && (d <= 8.0f);
      f32x4 LP = lgt[0][mt], LS = lgt[1][mt], LM = lgt[2][mt];

      float vm = v0 ? LP[0] : -INFINITY;
      if (v1) vm = fmaxf(vm, LP[1]);
      if (v2) vm = fmaxf(vm, LP[2]);
      if (v3) vm = fmaxf(vm, LP[3]);
      vm = fmaxf(vm, __shfl_xor(vm, 16));
      vm = fmaxf(vm, __shfl_xor(vm, 32));
      float e0 = v0 ? __expf(LP[0]-vm) : 0.f;
      float e1 = v1 ? __expf(LP[1]-vm) : 0.f;
      float e2 = v2 ? __expf(LP[2]-vm) : 0.f;
      float e3 = v3 ? __expf(LP[3]-vm) : 0.f;
      float ssum = e0+e1+e2+e3;
      ssum += __shfl_xor(ssum, 16);
      ssum += __shfl_xor(ssum, 32);
      float inv = 1.0f / ssum;
      float pi[4] = {e0*inv, e1*inv, e2*inv, e3*inv};

      float sg[4], mu[4], ll[4];
#pragma unroll
      for (int r = 0; r < 4; ++r) {
        sg[r] = (LS[r] > 0.f) ? (LS[r] + 1.4f) : (__expf(LS[r]) + 0.4f);
        mu[r] = (LM[r] > 0.f) ? (LM[r] + 1.0f) : __expf(LM[r]);
        float z = (d - mu[r]) / sg[r];
        ll[r] = -0.5f*z*z - __logf(sg[r]) - HLOG2PI;
      }

      if (q*4 < G_) {
        size_t o = (size_t)tok*G_ + q*4;
        *reinterpret_cast<float2*>(&out_pi[o]) = make_float2(pi[0], pi[1]);
        *reinterpret_cast<float2*>(&out_mu[o]) = make_float2(mu[0], mu[1]);
        *reinterpret_cast<float2*>(&out_sg[o]) = make_float2(sg[0], sg[1]);
        if (q*4+2 < G_) {
          *reinterpret_cast<float2*>(&out_pi[o+2]) = make_float2(pi[2], pi[3]);
          *reinterpret_cast<float2*>(&out_mu[o+2]) = make_float2(mu[2], mu[3]);
          *reinterpret_cast<float2*>(&out_sg[o+2]) = make_float2(sg[2], sg[3]);
        }
      }

      float a0 = v0 ? (__logf(pi[0]+1e-10f) + ll[0]) : -INFINITY;
      float a1x= v1 ? (__logf(pi[1]+1e-10f) + ll[1]) : -INFINITY;
      float a2 = v2 ? (__logf(pi[2]+1e-10f) + ll[2]) : -INFINITY;
      float a3 = v3 ? (__logf(pi[3]+1e-10f) + ll[3]) : -INFINITY;
      float m2 = fmaxf(fmaxf(a0,a1x), fmaxf(a2,a3));
      m2 = fmaxf(m2, __shfl_xor(m2, 16));
      m2 = fmaxf(m2, __shfl_xor(m2, 32));
      float s2 = (v0?__expf(a0-m2):0.f) + (v1?__expf(a1x-m2):0.f)
               + (v2?__expf(a2-m2):0.f) + (v3?__expf(a3-m2):0.f);
      s2 += __shfl_xor(s2, 16);
      s2 += __shfl_xor(s2, 32);
      float closs = -(m2 + __logf(s2));
      // s3 == sum(exp(a)) == s2 * exp(m2)  (eps-term <= 2e-10, negligible)
      float prob = s2 * __expf(m2) / (d*d + 1e-10f);

      if (lane < 16 && mk) { accP += prob; accL += closs; accC += 1.f; }
    }

    // ---- convert next tile ----
    if (s + 1 < NITER) {
#pragma unroll
      for (int mt = 0; mt < 2; ++mt) {
#pragma unroll
        for (int c = 0; c < 4; ++c) {
          float4 lo = fv[mt][2*c], hi = fv[mt][2*c+1];
          bf16x8 a;
          a[0]=f2bf(lo.x); a[1]=f2bf(lo.y); a[2]=f2bf(lo.z); a[3]=f2bf(lo.w);
          a[4]=f2bf(hi.x); a[5]=f2bf(hi.y); a[6]=f2bf(hi.z); a[7]=f2bf(hi.w);
          a1[mt][c] = a;
        }
        dpre[mt] = dnx[mt]; mpre[mt] = mnx[mt];
      }
    }
  }

  // ---- block reduce; block lies entirely in one batch b ----
  accP += __shfl_xor(accP, 1); accP += __shfl_xor(accP, 2);
  accP += __shfl_xor(accP, 4); accP += __shfl_xor(accP, 8);
  accL += __shfl_xor(accL, 1); accL += __shfl_xor(accL, 2);
  accL += __shfl_xor(accL, 4); accL += __shfl_xor(accL, 8);
  accC += __shfl_xor(accC, 1); accC += __shfl_xor(accC, 2);
  accC += __shfl_xor(accC, 4); accC += __shfl_xor(accC, 8);
  if (lane == 0) { sm.red[wave][0] = accP; sm.red[wave][1] = accL; sm.red[wave][2] = accC; }
  __syncthreads();
  if (tid == 0) {
    float sP = 0.f, sL = 0.f, sC = 0.f;
    for (int w = 0; w < WAVES; ++w) { sP += sm.red[w][0]; sL += sm.red[w][1]; sC += sm.red[w][2]; }
    int b = blockIdx.x >> 3;   // 8 blocks per batch
    atomicAdd(&out_score[b], sP);
    atomicAdd(&ws[0], sL);
    atomicAdd(&ws[1], sC);
  }
}

extern "C" void kernel_launch(void* const* d_in, const int* in_sizes, int n_in,
                              void* d_out, int out_size, void* d_ws, size_t ws_size,
                              hipStream_t stream) {
  const float* feat = (const float*)d_in[0];
  const float* dist = (const float*)d_in[1];
  const int* dmask = (const int*)d_in[2];
  float* out = (float*)d_out;
  float* ws  = (float*)d_ws;

  hipLaunchKernelGGL(init_kernel, dim3(1), dim3(64), 0, stream, out, ws);

  bool prep_ok = (ws_size >= (size_t)(WS_IMG_OFF + IMG_INSTS*1024));
  if (prep_ok) {
    short* img = (short*)((char*)d_ws + WS_IMG_OFF);
    hipLaunchKernelGGL(prep_kernel, dim3(116), dim3(256), 0, stream,
        (const float*)d_in[3],  (const float*)d_in[4],  (const float*)d_in[5],  (const float*)d_in[6],
        (const float*)d_in[7],  (const float*)d_in[8],  (const float*)d_in[9],  (const float*)d_in[10],
        (const float*)d_in[11], (const float*)d_in[12], (const float*)d_in[13], (const float*)d_in[14],
        img);
    hipLaunchKernelGGL((rtm_main<1>), dim3(TOKS/TPB), dim3(THREADS), 0, stream,
        feat, dist, dmask, (const float*)img,
        (const float*)d_in[3],  (const float*)d_in[4],  (const float*)d_in[5],  (const float*)d_in[6],
        (const float*)d_in[7],  (const float*)d_in[8],  (const float*)d_in[9],  (const float*)d_in[10],
        (const float*)d_in[11], (const float*)d_in[12], (const float*)d_in[13], (const float*)d_in[14],
        out, ws);
  } else {
    hipLaunchKernelGGL((rtm_main<0>), dim3(TOKS/TPB), dim3(THREADS), 0, stream,
        feat, dist, dmask, (const float*)nullptr,
        (const float*)d_in[3],  (const float*)d_in[4],  (const float*)d_in[5],  (const float*)d_in[6],
        (const float*)d_in[7],  (const float*)d_in[8],  (const float*)d_in[9],  (const float*)d_in[10],
        (const float*)d_in[11], (const float*)d_in[12], (const float*)d_in[13], (const float*)d_in[14],
        out, ws);
  }

  hipLaunchKernelGGL(fin_kernel, dim3(1), dim3(64), 0, stream, out, ws);
}

// Round 18
// 64.749 us; speedup vs baseline: 6.6697x; 1.0051x over previous
//
#include <hip/hip_runtime.h>
#include <hip/hip_bf16.h>
#include <math.h>

#define B_   32
#define N_   8192
#define H_   128
#define G_   10
#define TOKS (B_*N_)
#define THREADS 512
#define WAVES 8
#define NITER 4
#define TPB 1024   // 8 waves x 32 tok/tile x 4 tiles -> grid = exactly 256 blocks (1/CU)
#define LDW 136    // W1 row stride in shorts (272B)

typedef short bf16x8 __attribute__((ext_vector_type(8)));
typedef short bf16x4 __attribute__((ext_vector_type(4)));
typedef float f32x4 __attribute__((ext_vector_type(4)));

// ws image layout (shorts):
//   w1s [3][128][136]     W1^T padded            (52224 shorts)
//   w2f [3][8][64][4]     W2^T lane-major frags  (6144 shorts)  <- conflict-free b64
//   b1 [3][128] f32, b2 [3][16] f32
#define WS_IMG_OFF 256
#define IMG_W2   (3*H_*LDW)            // 52224
#define IMG_BF   (IMG_W2 + 3*8*64*4)   // 58368
#define IMG_BYTES (IMG_BF*2 + 3*H_*4 + 3*16*4)   // 118464
#define IMG_INSTS 116                  // ceil/1024; overshoot 320B -> red/pad (safe)

struct __align__(16) SMem {
  short w1s[3][H_][LDW];     // W1^T bf16: [head][hidden j][input i]
  short w2f[3][8][64][4];    // W2^T K16 A-frags, lane-major (r14-validated layout)
  float b1s[3][H_];
  float b2s[3][16];
  float red[WAVES][3];       // staging overshoot lands here; written post-compute
  char  pad[640];
};

__device__ __forceinline__ short f2bf(float f) {
  __hip_bfloat16 h = __float2bfloat16(f);
  union { __hip_bfloat16 h; short s; } u; u.h = h;
  return u.s;
}

__device__ __forceinline__ void async_copy16(void* lds_uniform, const void* gsrc_perlane) {
  __builtin_amdgcn_global_load_lds(
      (const __attribute__((address_space(1))) unsigned int*)gsrc_perlane,
      (__attribute__((address_space(3))) unsigned int*)lds_uniform,
      16, 0, 0);
}

__global__ __launch_bounds__(64) void init_kernel(float* out, float* ws) {
  int t = threadIdx.x;
  if (t < 33) out[t] = 0.0f;
  if (t < 2)  ws[t]  = 0.0f;
}

__global__ __launch_bounds__(64) void fin_kernel(float* out, const float* ws) {
  if (threadIdx.x == 0) out[32] = ws[0] / fmaxf(ws[1], 1.0f);
}

__global__ __launch_bounds__(256) void prep_kernel(
    const float* __restrict__ w1_0, const float* __restrict__ b1_0,
    const float* __restrict__ w2_0, const float* __restrict__ b2_0,
    const float* __restrict__ w1_1, const float* __restrict__ b1_1,
    const float* __restrict__ w2_1, const float* __restrict__ b2_1,
    const float* __restrict__ w1_2, const float* __restrict__ b1_2,
    const float* __restrict__ w2_2, const float* __restrict__ b2_2,
    short* __restrict__ img) {
  const float* w1p[3] = {w1_0, w1_1, w1_2};
  const float* w2p[3] = {w2_0, w2_1, w2_2};
  const float* b1p[3] = {b1_0, b1_1, b1_2};
  const float* b2p[3] = {b2_0, b2_1, b2_2};
  int t = blockIdx.x * 256 + threadIdx.x;
  int stride = gridDim.x * 256;
  // W1^T padded
  for (int idx = t; idx < 3*H_*LDW; idx += stride) {
    int h = idx / (H_*LDW), rem = idx - h*(H_*LDW);
    int j = rem / LDW, i = rem - j*LDW;
    img[idx] = (i < H_) ? f2bf(w1p[h][i*H_ + j]) : (short)0;
  }
  // W2^T lane-major K16 fragments: w2f[h][nt][lane] = W2^T[g=lane&15][k=nt*16+(lane>>4)*4+e]
  for (int idx = t; idx < 3*8*64; idx += stride) {
    int h = idx / 512, rem = idx - h*512;
    int nt = rem >> 6, ln = rem & 63;
    int qq = ln >> 4, lg = ln & 15;
#pragma unroll
    for (int e = 0; e < 4; ++e) {
      int k = nt*16 + qq*4 + e;
      img[IMG_W2 + idx*4 + e] = (lg < G_) ? f2bf(w2p[h][k*G_ + lg]) : (short)0;
    }
  }
  float* bimg = (float*)(img + IMG_BF);
  if (t < 3*H_ + 3*16) {
    if (t < 3*H_) { int h = t >> 7, j = t & 127; bimg[t] = b1p[h][j]; }
    else { int i2 = t - 3*H_; int h = i2 >> 4, g = i2 & 15;
           bimg[t] = (g < G_) ? b2p[h][g] : 0.0f; }
  }
}

template<int PREP>
__global__ __launch_bounds__(THREADS, 2)   // 256-reg cap (128 arch + 64 acc), r17-proven
void rtm_main(const float* __restrict__ feat,
              const float* __restrict__ dist,
              const int* __restrict__ dmask,
              const float* __restrict__ img,
              const float* __restrict__ w1_0, const float* __restrict__ b1_0,
              const float* __restrict__ w2_0, const float* __restrict__ b2_0,
              const float* __restrict__ w1_1, const float* __restrict__ b1_1,
              const float* __restrict__ w2_1, const float* __restrict__ b2_1,
              const float* __restrict__ w1_2, const float* __restrict__ b1_2,
              const float* __restrict__ w2_2, const float* __restrict__ b2_2,
              float* __restrict__ out, float* __restrict__ ws) {
  __shared__ SMem sm;

  const int tid  = threadIdx.x;
  const int wave = tid >> 6;
  const int lane = tid & 63;
  const int q  = lane >> 4;
  const int lg = lane & 15;
  const long wbase = (long)blockIdx.x * TPB + (long)wave * (32*NITER);

  // ---- prologue: issue tile-0 loads ----
  float4 fv[2][8];
  float dpre[2]; int mpre[2];
#pragma unroll
  for (int mt = 0; mt < 2; ++mt) {
    const float* fr = feat + (wbase + mt*16 + lg) * (long)H_;
#pragma unroll
    for (int c = 0; c < 4; ++c) {
      const float4* p = reinterpret_cast<const float4*>(fr + c*32 + q*8);
      fv[mt][2*c]   = p[0];
      fv[mt][2*c+1] = p[1];
    }
    dpre[mt] = dist[wbase + mt*16 + lg];
    mpre[mt] = dmask[wbase + mt*16 + lg];
  }

  // ---- stage weight image to LDS (async; once per CU) ----
  if constexpr (PREP) {
    char* smb = (char*)&sm;
    const char* gimg = (const char*)img;
    for (int i = wave; i < IMG_INSTS; i += WAVES)
      async_copy16(smb + i*1024, gimg + i*1024 + lane*16);
  } else {
    const float* w1p[3] = {w1_0, w1_1, w1_2};
    const float* w2p[3] = {w2_0, w2_1, w2_2};
    const float* b1p[3] = {b1_0, b1_1, b1_2};
    const float* b2p[3] = {b2_0, b2_1, b2_2};
    for (int h = 0; h < 3; ++h) {
      for (int idx = tid; idx < H_*H_; idx += THREADS) {
        int i = idx >> 7, j = idx & 127;
        sm.w1s[h][j][i] = f2bf(w1p[h][idx]);
      }
      for (int idx = tid; idx < 8*64; idx += THREADS) {
        int nt = idx >> 6, ln = idx & 63;
        int qq = ln >> 4, lgg = ln & 15;
#pragma unroll
        for (int e = 0; e < 4; ++e) {
          int k = nt*16 + qq*4 + e;
          sm.w2f[h][nt][ln][e] = (lgg < G_) ? f2bf(w2p[h][k*G_ + lgg]) : (short)0;
        }
      }
      if (tid < H_) sm.b1s[h][tid] = b1p[h][tid];
      if (tid < 16) sm.b2s[h][tid] = (tid < G_) ? b2p[h][tid] : 0.0f;
    }
  }

  // ---- convert tile 0 while staging is in flight ----
  bf16x8 a1[2][4];   // B-frag (K=32): lane holds B[k=(lane>>4)*8+e][tok=lane&15]
#pragma unroll
  for (int mt = 0; mt < 2; ++mt)
#pragma unroll
    for (int c = 0; c < 4; ++c) {
      float4 lo = fv[mt][2*c], hi = fv[mt][2*c+1];
      bf16x8 a;
      a[0]=f2bf(lo.x); a[1]=f2bf(lo.y); a[2]=f2bf(lo.z); a[3]=f2bf(lo.w);
      a[4]=f2bf(hi.x); a[5]=f2bf(hi.y); a[6]=f2bf(hi.z); a[7]=f2bf(hi.w);
      a1[mt][c] = a;
    }

  __syncthreads();   // weights visible; drains global_load_lds

  float* out_score = out;
  float* out_pi = out + 33;
  float* out_mu = out + 33 + (size_t)TOKS*G_;
  float* out_sg = out + 33 + 2*(size_t)TOKS*G_;
  const float HLOG2PI = 0.91893853320467274f;
  const bool v0 = (q*4+0) < G_, v1 = (q*4+1) < G_, v2 = (q*4+2) < G_, v3 = (q*4+3) < G_;

  float accP = 0.f, accL = 0.f, accC = 0.f;

  // ---- pipelined tile loop ----
#pragma unroll
  for (int s = 0; s < NITER; ++s) {
    float dnx[2]; int mnx[2];
    if (s + 1 < NITER) {
#pragma unroll
      for (int mt = 0; mt < 2; ++mt) {
        const float* fr = feat + (wbase + (s+1)*32 + mt*16 + lg) * (long)H_;
#pragma unroll
        for (int c = 0; c < 4; ++c) {
          const float4* p = reinterpret_cast<const float4*>(fr + c*32 + q*8);
          fv[mt][2*c]   = p[0];
          fv[mt][2*c+1] = p[1];
        }
        dnx[mt] = dist[wbase + (s+1)*32 + mt*16 + lg];
        mnx[mt] = dmask[wbase + (s+1)*32 + mt*16 + lg];
      }
    }

    // ---- compute tile s ----
    f32x4 lgt[3][2];
#pragma unroll
    for (int h = 0; h < 3; ++h) {
      // W2^T K16 A-frags: lane-major image, conflict-free ds_read_b64
      bf16x4 w2fr[8];
#pragma unroll
      for (int nt = 0; nt < 8; ++nt)
        w2fr[nt] = *reinterpret_cast<const bf16x4*>(sm.w2f[h][nt][lane]);

      // layer 1: init accumulator with BIAS (r17)
      f32x4 acc[2][8];
#pragma unroll
      for (int nt = 0; nt < 8; ++nt) {
        f32x4 b1v = *reinterpret_cast<const f32x4*>(&sm.b1s[h][nt*16 + q*4]);
        acc[0][nt] = b1v;
        acc[1][nt] = b1v;
      }
#pragma unroll
      for (int c = 0; c < 4; ++c) {
#pragma unroll
        for (int nt = 0; nt < 8; ++nt) {
          bf16x8 wfr = *reinterpret_cast<const bf16x8*>(&sm.w1s[h][nt*16 + lg][c*32 + q*8]);
          acc[0][nt] = __builtin_amdgcn_mfma_f32_16x16x32_bf16(wfr, a1[0][c], acc[0][nt], 0, 0, 0);
          acc[1][nt] = __builtin_amdgcn_mfma_f32_16x16x32_bf16(wfr, a1[1][c], acc[1][nt], 0, 0, 0);
        }
      }
#pragma unroll
      for (int mt = 0; mt < 2; ++mt) {
        // layer 2 in registers: init chains with b2v (r17)
        f32x4 b2v = *reinterpret_cast<const f32x4*>(&sm.b2s[h][q*4]);
        f32x4 lacc0 = b2v;
        f32x4 lacc1 = (f32x4){0.f,0.f,0.f,0.f};
#pragma unroll
        for (int nt = 0; nt < 8; ++nt) {
          bf16x4 pkv;
#pragma unroll
          for (int r = 0; r < 4; ++r)
            pkv[r] = f2bf(fmaxf(acc[mt][nt][r], 0.0f));
          if (nt & 1)
            lacc1 = __builtin_amdgcn_mfma_f32_16x16x16bf16_1k(w2fr[nt], pkv, lacc1, 0, 0, 0);
          else
            lacc0 = __builtin_amdgcn_mfma_f32_16x16x16bf16_1k(w2fr[nt], pkv, lacc0, 0, 0, 0);
        }
        lgt[h][mt] = lacc0 + lacc1;   // row = g = q*4+r, col = token = lg
      }
    }

    // ---- epilogue tile s (r17 form: s3 = s2*exp(m2) fusion) ----
#pragma unroll
    for (int mt = 0; mt < 2; ++mt) {
      long tok = wbase + s*32 + mt*16 + lg;
      float d  = dpre[mt];
      bool  mk = (mpre[mt] != 0) && (d <= 8.0f);
      f32x4 LP = lgt[0][mt], LS = lgt[1][mt], LM = lgt[2][mt];

      float vm = v0 ? LP[0] : -INFINITY;
      if (v1) vm = fmaxf(vm, LP[1]);
      if (v2) vm = fmaxf(vm, LP[2]);
      if (v3) vm = fmaxf(vm, LP[3]);
      vm = fmaxf(vm, __shfl_xor(vm, 16));
      vm = fmaxf(vm, __shfl_xor(vm, 32));
      float e0 = v0 ? __expf(LP[0]-vm) : 0.f;
      float e1 = v1 ? __expf(LP[1]-vm) : 0.f;
      float e2 = v2 ? __expf(LP[2]-vm) : 0.f;
      float e3 = v3 ? __expf(LP[3]-vm) : 0.f;
      float ssum = e0+e1+e2+e3;
      ssum += __shfl_xor(ssum, 16);
      ssum += __shfl_xor(ssum, 32);
      float inv = 1.0f / ssum;
      float pi[4] = {e0*inv, e1*inv, e2*inv, e3*inv};

      float sg[4], mu[4], ll[4];
#pragma unroll
      for (int r = 0; r < 4; ++r) {
        sg[r] = (LS[r] > 0.f) ? (LS[r] + 1.4f) : (__expf(LS[r]) + 0.4f);
        mu[r] = (LM[r] > 0.f) ? (LM[r] + 1.0f) : __expf(LM[r]);
        float z = (d - mu[r]) / sg[r];
        ll[r] = -0.5f*z*z - __logf(sg[r]) - HLOG2PI;
      }

      if (q*4 < G_) {
        size_t o = (size_t)tok*G_ + q*4;
        *reinterpret_cast<float2*>(&out_pi[o]) = make_float2(pi[0], pi[1]);
        *reinterpret_cast<float2*>(&out_mu[o]) = make_float2(mu[0], mu[1]);
        *reinterpret_cast<float2*>(&out_sg[o]) = make_float2(sg[0], sg[1]);
        if (q*4+2 < G_) {
          *reinterpret_cast<float2*>(&out_pi[o+2]) = make_float2(pi[2], pi[3]);
          *reinterpret_cast<float2*>(&out_mu[o+2]) = make_float2(mu[2], mu[3]);
          *reinterpret_cast<float2*>(&out_sg[o+2]) = make_float2(sg[2], sg[3]);
        }
      }

      float a0 = v0 ? (__logf(pi[0]+1e-10f) + ll[0]) : -INFINITY;
      float a1x= v1 ? (__logf(pi[1]+1e-10f) + ll[1]) : -INFINITY;
      float a2 = v2 ? (__logf(pi[2]+1e-10f) + ll[2]) : -INFINITY;
      float a3 = v3 ? (__logf(pi[3]+1e-10f) + ll[3]) : -INFINITY;
      float m2 = fmaxf(fmaxf(a0,a1x), fmaxf(a2,a3));
      m2 = fmaxf(m2, __shfl_xor(m2, 16));
      m2 = fmaxf(m2, __shfl_xor(m2, 32));
      float s2 = (v0?__expf(a0-m2):0.f) + (v1?__expf(a1x-m2):0.f)
               + (v2?__expf(a2-m2):0.f) + (v3?__expf(a3-m2):0.f);
      s2 += __shfl_xor(s2, 16);
      s2 += __shfl_xor(s2, 32);
      float closs = -(m2 + __logf(s2));
      // s3 == sum(exp(a)) == s2 * exp(m2)  (eps-term <= 2e-10, negligible)
      float prob = s2 * __expf(m2) / (d*d + 1e-10f);

      if (lane < 16 && mk) { accP += prob; accL += closs; accC += 1.f; }
    }

    // ---- convert next tile ----
    if (s + 1 < NITER) {
#pragma unroll
      for (int mt = 0; mt < 2; ++mt) {
#pragma unroll
        for (int c = 0; c < 4; ++c) {
          float4 lo = fv[mt][2*c], hi = fv[mt][2*c+1];
          bf16x8 a;
          a[0]=f2bf(lo.x); a[1]=f2bf(lo.y); a[2]=f2bf(lo.z); a[3]=f2bf(lo.w);
          a[4]=f2bf(hi.x); a[5]=f2bf(hi.y); a[6]=f2bf(hi.z); a[7]=f2bf(hi.w);
          a1[mt][c] = a;
        }
        dpre[mt] = dnx[mt]; mpre[mt] = mnx[mt];
      }
    }
  }

  // ---- block reduce; block lies entirely in one batch b ----
  accP += __shfl_xor(accP, 1); accP += __shfl_xor(accP, 2);
  accP += __shfl_xor(accP, 4); accP += __shfl_xor(accP, 8);
  accL += __shfl_xor(accL, 1); accL += __shfl_xor(accL, 2);
  accL += __shfl_xor(accL, 4); accL += __shfl_xor(accL, 8);
  accC += __shfl_xor(accC, 1); accC += __shfl_xor(accC, 2);
  accC += __shfl_xor(accC, 4); accC += __shfl_xor(accC, 8);
  if (lane == 0) { sm.red[wave][0] = accP; sm.red[wave][1] = accL; sm.red[wave][2] = accC; }
  __syncthreads();
  if (tid == 0) {
    float sP = 0.f, sL = 0.f, sC = 0.f;
    for (int w = 0; w < WAVES; ++w) { sP += sm.red[w][0]; sL += sm.red[w][1]; sC += sm.red[w][2]; }
    int b = blockIdx.x >> 3;   // 8 blocks per batch
    atomicAdd(&out_score[b], sP);
    atomicAdd(&ws[0], sL);
    atomicAdd(&ws[1], sC);
  }
}

extern "C" void kernel_launch(void* const* d_in, const int* in_sizes, int n_in,
                              void* d_out, int out_size, void* d_ws, size_t ws_size,
                              hipStream_t stream) {
  const float* feat = (const float*)d_in[0];
  const float* dist = (const float*)d_in[1];
  const int* dmask = (const int*)d_in[2];
  float* out = (float*)d_out;
  float* ws  = (float*)d_ws;

  hipLaunchKernelGGL(init_kernel, dim3(1), dim3(64), 0, stream, out, ws);

  bool prep_ok = (ws_size >= (size_t)(WS_IMG_OFF + IMG_INSTS*1024));
  if (prep_ok) {
    short* img = (short*)((char*)d_ws + WS_IMG_OFF);
    hipLaunchKernelGGL(prep_kernel, dim3(116), dim3(256), 0, stream,
        (const float*)d_in[3],  (const float*)d_in[4],  (const float*)d_in[5],  (const float*)d_in[6],
        (const float*)d_in[7],  (const float*)d_in[8],  (const float*)d_in[9],  (const float*)d_in[10],
        (const float*)d_in[11], (const float*)d_in[12], (const float*)d_in[13], (const float*)d_in[14],
        img);
    hipLaunchKernelGGL((rtm_main<1>), dim3(TOKS/TPB), dim3(THREADS), 0, stream,
        feat, dist, dmask, (const float*)img,
        (const float*)d_in[3],  (const float*)d_in[4],  (const float*)d_in[5],  (const float*)d_in[6],
        (const float*)d_in[7],  (const float*)d_in[8],  (const float*)d_in[9],  (const float*)d_in[10],
        (const float*)d_in[11], (const float*)d_in[12], (const float*)d_in[13], (const float*)d_in[14],
        out, ws);
  } else {
    hipLaunchKernelGGL((rtm_main<0>), dim3(TOKS/TPB), dim3(THREADS), 0, stream,
        feat, dist, dmask, (const float*)nullptr,
        (const float*)d_in[3],  (const float*)d_in[4],  (const float*)d_in[5],  (const float*)d_in[6],
        (const float*)d_in[7],  (const float*)d_in[8],  (const float*)d_in[9],  (const float*)d_in[10],
        (const float*)d_in[11], (const float*)d_in[12], (const float*)d_in[13], (const float*)d_in[14],
        out, ws);
  }

  hipLaunchKernelGGL(fin_kernel, dim3(1), dim3(64), 0, stream, out, ws);
}